// Round 1
// baseline (1328.167 us; speedup 1.0000x reference)
//
#include <hip/hip_runtime.h>

// ---------------------------------------------------------------------------
// MultiDimensionalLSTM on MI355X.
// B=32, C=32, Y=X=128, win 4x4 -> grid 32x32 cells, F=512, R=128, gates 5R=640.
// Input projection hoisted to one split-bf16 MFMA GEMM (unchanged).
//
// R6 RESTRUCTURE of the recurrence: slice by BATCH, not by r.
//   64 blocks = (batch-set s in {0,1} x 16 batches, row h in [0,32)).
//   Each block computes the FULL 640-wide gate vector for its 16 batches:
//     - left dep (t-1): INTRA-BLOCK. new h goes through LDS (h2h/h2l),
//       c_left lives in registers. Zero global hops on the across-edges.
//     - up dep (t-32): single-producer (s,h-1) -> single-consumer (s,h).
//       One release store per step, one relaxed poll. No 16-way contention.
//   Longest path: 31 cross-block hops + 63 local steps (was 63 stages each
//   paying TWO 16-producer publish/poll round trips -> 11.2 us/stage).
//   Wh (640x256 split-bf16 = 655 KB) does not fit LDS -> lives in VGPRs:
//   8 waves x 5 n-tiles x 8 k-tiles x (hi+lo) = 320 VGPR/lane, loaded once.
//   All weight indexing fully unrolled (static) so fragments stay in regs.
// Publication recipe unchanged from R5 (proven): sc1 relaxed-atomic data
// stores + RELEASE flag publication (vmcnt(0)+wbl2+store). R4's relaxed-flag
// publication gave stale reads; R3's acq_rel threadfence cost 2.1 ms.
// ---------------------------------------------------------------------------

typedef unsigned short u16;
typedef unsigned int u32;
typedef unsigned long long u64;
typedef __attribute__((ext_vector_type(8))) short short8;     // 8 bf16 (4 VGPRs)
typedef __attribute__((ext_vector_type(8))) unsigned short us8;
typedef __attribute__((ext_vector_type(4))) float floatx4;

union Frag { u64 q[2]; short8 s; };

__device__ inline u16 f2bf(float f) {               // RNE fp32 -> bf16
  unsigned u = __float_as_uint(f);
  u += 0x7fffu + ((u >> 16) & 1u);
  return (u16)(u >> 16);
}
__device__ inline float bf2f(u16 v) { return __uint_as_float(((unsigned)v) << 16); }

__device__ inline void async16(u16* lds, const u16* g) {
  __builtin_amdgcn_global_load_lds((const __attribute__((address_space(1))) void*)g,
                                   (__attribute__((address_space(3))) void*)lds, 16, 0, 0);
}

__device__ inline float sigf(float x) { return 1.f / (1.f + __expf(-x)); }
__device__ inline float tanh_fast(float x) { return 1.f - 2.f / (__expf(2.f * x) + 1.f); }

// Relaxed agent-scope primitives: sc1 loads/stores, straight to coherence point.
__device__ inline void waitflag(const int* f, int target) {
  while (__hip_atomic_load(f, __ATOMIC_RELAXED, __HIP_MEMORY_SCOPE_AGENT) < target)
    __builtin_amdgcn_s_sleep(1);
  __asm__ __volatile__("" ::: "memory");   // compiler barrier: no load hoisting
}
__device__ inline u64 aload64(const u64* p) {
  return __hip_atomic_load(p, __ATOMIC_RELAXED, __HIP_MEMORY_SCOPE_AGENT);
}
__device__ inline void astore32(u32* p, u32 v) {
  __hip_atomic_store(p, v, __ATOMIC_RELAXED, __HIP_MEMORY_SCOPE_AGENT);
}
__device__ inline void astore64(u64* p, u64 v) {
  __hip_atomic_store(p, v, __ATOMIC_RELAXED, __HIP_MEMORY_SCOPE_AGENT);
}

// ---------------------------------------------------------------------------
// Prep 1: W [768][640] fp32 -> WxT_{h,l} [640 pcol][512 k], WhT_{h,l} [640][256],
// biasp [640]. pcol = r*5+g  <->  orig col g*128+r (gate-interleaved).
// ---------------------------------------------------------------------------
__global__ __launch_bounds__(256) void k_wprep(const float* __restrict__ W,
                                               const float* __restrict__ bias,
                                               u16* __restrict__ WxT_h, u16* __restrict__ WxT_l,
                                               u16* __restrict__ WhT_h, u16* __restrict__ WhT_l,
                                               float* __restrict__ biasp) {
  int pcol = blockIdx.x;                       // 0..639
  int col  = (pcol % 5) * 128 + pcol / 5;      // original gate column
  for (int k = threadIdx.x; k < 768; k += 256) {
    float v = W[(size_t)k * 640 + col];
    u16 hi = f2bf(v);
    u16 lo = f2bf(v - bf2f(hi));
    if (k < 512) { WxT_h[(size_t)pcol * 512 + k] = hi; WxT_l[(size_t)pcol * 512 + k] = lo; }
    else { WhT_h[(size_t)pcol * 256 + (k - 512)] = hi; WhT_l[(size_t)pcol * 256 + (k - 512)] = lo; }
  }
  if (threadIdx.x == 0) biasp[pcol] = bias[col];
}

// ---------------------------------------------------------------------------
// Prep 2: gather x [B,C,Y,X] -> xs hi/lo [t][b][f].
// xs[t][b][f] = x[b][f&31][t>>3][(t&7)*16 + (f>>5)]
// ---------------------------------------------------------------------------
__global__ __launch_bounds__(256) void k_xgather(const float* __restrict__ x,
                                                 u16* __restrict__ xs_h,
                                                 u16* __restrict__ xs_l) {
  int lane = threadIdx.x & 63;
  int pair = blockIdx.x * 4 + (threadIdx.x >> 6);  // t*32+b
  int t = pair >> 5, b = pair & 31;
  int y = t >> 3, x0 = (t & 7) * 16;
  int j = lane >> 2;
  int cbase = (lane & 3) * 8;
  const float* src = x + ((size_t)b * 32 * 128 + y) * 128 + x0 + j;
  us8 vh, vl;
#pragma unroll
  for (int u = 0; u < 8; ++u) {
    float f = src[(size_t)(cbase + u) * 16384];
    u16 hi = f2bf(f);
    vh[u] = hi;
    vl[u] = f2bf(f - bf2f(hi));
  }
  *(us8*)(xs_h + (size_t)pair * 512 + lane * 8) = vh;
  *(us8*)(xs_l + (size_t)pair * 512 + lane * 8) = vl;
}

// ---------------------------------------------------------------------------
// Input GEMM (split-bf16): M=32768, N=640, K=512. 128x128 tile, BK=32.
// ---------------------------------------------------------------------------
__global__ __launch_bounds__(256) void k_gemm_in(const u16* __restrict__ xs_h,
                                                 const u16* __restrict__ xs_l,
                                                 const u16* __restrict__ WxT_h,
                                                 const u16* __restrict__ WxT_l,
                                                 const float* __restrict__ biasp,
                                                 float* __restrict__ Gp) {
  __shared__ u16 Ah[128 * 32], Al[128 * 32];
  __shared__ u16 Bh[128 * 32], Bl[128 * 32];
  const int tid = threadIdx.x;
  const int wv = tid >> 6, lane = tid & 63;
  const int quad = lane >> 4, l16 = lane & 15;
  const int m0 = blockIdx.x * 128;
  const int n0 = blockIdx.y * 128;
  const int arow = lane >> 2;
  const int acol = (lane & 3) * 8;

  floatx4 acc[4][4] = {};

  for (int kt = 0; kt < 512; kt += 32) {
#pragma unroll
    for (int i = 0; i < 2; ++i) {
      int chunk = wv * 2 + i;
      int row = chunk * 16 + arow;
      size_t aoff = (size_t)(m0 + row) * 512 + kt + acol;
      size_t boff = (size_t)(n0 + row) * 512 + kt + acol;
      async16(&Ah[chunk * 512 + lane * 8], xs_h + aoff);
      async16(&Al[chunk * 512 + lane * 8], xs_l + aoff);
      async16(&Bh[chunk * 512 + lane * 8], WxT_h + boff);
      async16(&Bl[chunk * 512 + lane * 8], WxT_l + boff);
    }
    __syncthreads();
    short8 afh[4], afl[4], bfh[4], bfl[4];
#pragma unroll
    for (int mt = 0; mt < 4; ++mt) {
      int ro = ((wv & 1) * 64 + mt * 16 + l16) * 32 + quad * 8;
      afh[mt] = *(const short8*)&Ah[ro];
      afl[mt] = *(const short8*)&Al[ro];
    }
#pragma unroll
    for (int nt = 0; nt < 4; ++nt) {
      int ro = ((wv >> 1) * 64 + nt * 16 + l16) * 32 + quad * 8;
      bfh[nt] = *(const short8*)&Bh[ro];
      bfl[nt] = *(const short8*)&Bl[ro];
    }
#pragma unroll
    for (int mt = 0; mt < 4; ++mt)
#pragma unroll
      for (int nt = 0; nt < 4; ++nt) {
        floatx4 a = acc[mt][nt];
        a = __builtin_amdgcn_mfma_f32_16x16x32_bf16(afl[mt], bfh[nt], a, 0, 0, 0);
        a = __builtin_amdgcn_mfma_f32_16x16x32_bf16(afh[mt], bfl[nt], a, 0, 0, 0);
        a = __builtin_amdgcn_mfma_f32_16x16x32_bf16(afh[mt], bfh[nt], a, 0, 0, 0);
        acc[mt][nt] = a;
      }
    __syncthreads();
  }
#pragma unroll
  for (int nt = 0; nt < 4; ++nt) {
    int n = n0 + (wv >> 1) * 64 + nt * 16 + l16;
    float bv = biasp[n];
#pragma unroll
    for (int mt = 0; mt < 4; ++mt) {
      int m = m0 + (wv & 1) * 64 + mt * 16 + quad * 4;
#pragma unroll
      for (int r = 0; r < 4; ++r)
        Gp[(size_t)(m + r) * 640 + n] = acc[mt][nt][r] + bv;
    }
  }
}

// ---------------------------------------------------------------------------
// Persistent recurrence, batch-sliced. Grid 64: blockIdx = s + 2*h
// (producers of row h-1 have lower IDs). Block 512 threads = 8 waves.
// Wave wv owns pcols [wv*80, wv*80+80) (5 n-tiles of 16); M=16 batches shared.
// Per step per wave: 5nt x 8ks x 3 = 120 MFMAs (h2 half local, h1 half remote).
// LDS: Gs gates 16x654 f32 (41.9 KB, 654 stride -> conflict-spread) +
//      h2 hi/lo 16x136 u16 (8.7 KB) = 50.6 KB.
// ---------------------------------------------------------------------------
__global__ __launch_bounds__(512, 1) void k_rec(const u16* __restrict__ WhT_h,
                                                const u16* __restrict__ WhT_l,
                                                const float* __restrict__ Gp,
                                                u64* __restrict__ cbuf,       // [t*32+b][64] fp32 pairs
                                                u16* __restrict__ hbf_h,      // [t*32+b][128]
                                                u16* __restrict__ hbf_l,
                                                float* __restrict__ out,
                                                int* __restrict__ flags) {
  __shared__ float Gs[16 * 654];
  __shared__ u16 h2h[16 * 136], h2l[16 * 136];   // row pad 136: 2-way-free frag reads

  const int s = blockIdx.x & 1, h = blockIdx.x >> 1;
  const int sb = s * 16;                 // global batch base of this set
  const int tid = threadIdx.x;
  const int wv = tid >> 6, lane = tid & 63;
  const int quad = lane >> 4, l16 = lane & 15;
  const int n0w = wv * 80;               // this wave's pcol base
  const int rp = lane;                   // epilogue r-pair 0..63 (r = 2*rp)
  const int fid = s * 32 + h;

  // ---- Wh fragments -> VGPRs, once. Fully static indexing (no scratch). ----
  short8 Bh[5][8], Bl[5][8];
#pragma unroll
  for (int nt = 0; nt < 5; ++nt) {
    const u16* ph = WhT_h + (size_t)(n0w + nt * 16 + l16) * 256 + quad * 8;
    const u16* pl = WhT_l + (size_t)(n0w + nt * 16 + l16) * 256 + quad * 8;
#pragma unroll
    for (int ks = 0; ks < 8; ++ks) {
      Bh[nt][ks] = *(const short8*)(ph + ks * 32);
      Bl[nt][ks] = *(const short8*)(pl + ks * 32);
    }
  }

  // c_left registers: unit0 = batch wv, unit1 = batch 8+wv (pair each)
  float cl00 = 0.f, cl01 = 0.f, cl10 = 0.f, cl11 = 0.f;

  for (int w = 0; w < 32; ++w) {
    const int t = h * 32 + w;
    const bool upok = t > 32;            // faithful off-by-one: (1,0) gets no up

    // Gp prefetch (plain cached loads; independent of flags -> hides under wait)
    float g0[10], g1[10];
    {
      const float* p0 = Gp + ((size_t)t * 32 + sb + wv) * 640 + rp * 10;
      const float* p1 = Gp + ((size_t)t * 32 + sb + 8 + wv) * 640 + rp * 10;
#pragma unroll
      for (int i = 0; i < 10; ++i) { g0[i] = p0[i]; g1[i] = p1[i]; }
    }

    Frag f1h[4], f1l[4];
    float c1a0 = 0.f, c1b0 = 0.f, c1a1 = 0.f, c1b1 = 0.f;
    if (upok) {
      waitflag(&flags[fid - 1], w + 1);  // single producer: block (s, h-1)
      const u64* srch = (const u64*)hbf_h;
      const u64* srcl = (const u64*)hbf_l;
#pragma unroll
      for (int ks = 0; ks < 4; ++ks) {   // h1 A-frags: batch = l16, k = ks*32+quad*8
        size_t bi = (((size_t)(t - 32) * 32 + sb + l16) * 128 + ks * 32 + quad * 8) >> 2;
        f1h[ks].q[0] = aload64(srch + bi);
        f1h[ks].q[1] = aload64(srch + bi + 1);
        f1l[ks].q[0] = aload64(srcl + bi);
        f1l[ks].q[1] = aload64(srcl + bi + 1);
      }
      u64 cp0 = aload64(cbuf + ((size_t)(t - 32) * 32 + sb + wv) * 64 + rp);
      u64 cp1 = aload64(cbuf + ((size_t)(t - 32) * 32 + sb + 8 + wv) * 64 + rp);
      c1a0 = __uint_as_float((u32)cp0); c1b0 = __uint_as_float((u32)(cp0 >> 32));
      c1a1 = __uint_as_float((u32)cp1); c1b1 = __uint_as_float((u32)(cp1 >> 32));
    }

    floatx4 acc[5] = {};

    if (w > 0) {                         // left half: h2 from LDS, fully local
#pragma unroll
      for (int ks = 0; ks < 4; ++ks) {
        short8 ah = *(const short8*)&h2h[l16 * 136 + ks * 32 + quad * 8];
        short8 al = *(const short8*)&h2l[l16 * 136 + ks * 32 + quad * 8];
#pragma unroll
        for (int nt = 0; nt < 5; ++nt) {
          floatx4 a = acc[nt];
          a = __builtin_amdgcn_mfma_f32_16x16x32_bf16(al, Bh[nt][ks + 4], a, 0, 0, 0);
          a = __builtin_amdgcn_mfma_f32_16x16x32_bf16(ah, Bl[nt][ks + 4], a, 0, 0, 0);
          a = __builtin_amdgcn_mfma_f32_16x16x32_bf16(ah, Bh[nt][ks + 4], a, 0, 0, 0);
          acc[nt] = a;
        }
      }
    }
    if (upok) {                          // up half: h1 loads have been in flight
#pragma unroll
      for (int ks = 0; ks < 4; ++ks)
#pragma unroll
        for (int nt = 0; nt < 5; ++nt) {
          floatx4 a = acc[nt];
          a = __builtin_amdgcn_mfma_f32_16x16x32_bf16(f1l[ks].s, Bh[nt][ks], a, 0, 0, 0);
          a = __builtin_amdgcn_mfma_f32_16x16x32_bf16(f1h[ks].s, Bl[nt][ks], a, 0, 0, 0);
          a = __builtin_amdgcn_mfma_f32_16x16x32_bf16(f1h[ks].s, Bh[nt][ks], a, 0, 0, 0);
          acc[nt] = a;
        }
    }

    // acc -> Gs  (C layout: row = quad*4+r -> batch, col = l16 -> pcol-local)
#pragma unroll
    for (int nt = 0; nt < 5; ++nt)
#pragma unroll
      for (int r = 0; r < 4; ++r)
        Gs[(quad * 4 + r) * 654 + n0w + nt * 16 + l16] = acc[nt][r];
    __syncthreads();

    // ---- epilogue unit 0: batch b = wv ----
    {
      const float* gp = &Gs[wv * 654 + rp * 10];
      float gi0 = gp[0] + g0[0], gj0 = gp[1] + g0[1], ga0 = gp[2] + g0[2],
            gb0 = gp[3] + g0[3], go0 = gp[4] + g0[4];
      float gi1 = gp[5] + g0[5], gj1 = gp[6] + g0[6], ga1 = gp[7] + g0[7],
            gb1 = gp[8] + g0[8], go1 = gp[9] + g0[9];
      float c20 = (w > 0) ? cl00 : 0.f;
      float c21 = (w > 0) ? cl01 : 0.f;
      float nc0 = c1a0 * sigf(ga0) + c20 * sigf(gb0) + sigf(gi0) * tanh_fast(gj0);
      float nh0 = tanh_fast(nc0) * sigf(go0);
      float nc1 = c1b0 * sigf(ga1) + c21 * sigf(gb1) + sigf(gi1) * tanh_fast(gj1);
      float nh1 = tanh_fast(nc1) * sigf(go1);
      cl00 = nc0; cl01 = nc1;
      u32 hi0 = f2bf(nh0), lo0 = f2bf(nh0 - bf2f((u16)hi0));
      u32 hi1 = f2bf(nh1), lo1 = f2bf(nh1 - bf2f((u16)hi1));
      const int gb = sb + wv;
      size_t pidx = ((size_t)t * 32 + gb) * 64 + rp;
      astore32((u32*)hbf_h + pidx, hi0 | (hi1 << 16));
      astore32((u32*)hbf_l + pidx, lo0 | (lo1 << 16));
      astore64(cbuf + pidx, (u64)__float_as_uint(nc0) | ((u64)__float_as_uint(nc1) << 32));
      astore64((u64*)(out + (((size_t)gb * 32 + h) * 32 + w) * 128 + rp * 2),
               (u64)__float_as_uint(nh0) | ((u64)__float_as_uint(nh1) << 32));
      *(u32*)&h2h[wv * 136 + rp * 2] = hi0 | (hi1 << 16);
      *(u32*)&h2l[wv * 136 + rp * 2] = lo0 | (lo1 << 16);
    }
    // ---- epilogue unit 1: batch b = 8 + wv ----
    {
      const float* gp = &Gs[(8 + wv) * 654 + rp * 10];
      float gi0 = gp[0] + g1[0], gj0 = gp[1] + g1[1], ga0 = gp[2] + g1[2],
            gb0 = gp[3] + g1[3], go0 = gp[4] + g1[4];
      float gi1 = gp[5] + g1[5], gj1 = gp[6] + g1[6], ga1 = gp[7] + g1[7],
            gb1 = gp[8] + g1[8], go1 = gp[9] + g1[9];
      float c20 = (w > 0) ? cl10 : 0.f;
      float c21 = (w > 0) ? cl11 : 0.f;
      float nc0 = c1a1 * sigf(ga0) + c20 * sigf(gb0) + sigf(gi0) * tanh_fast(gj0);
      float nh0 = tanh_fast(nc0) * sigf(go0);
      float nc1 = c1b1 * sigf(ga1) + c21 * sigf(gb1) + sigf(gi1) * tanh_fast(gj1);
      float nh1 = tanh_fast(nc1) * sigf(go1);
      cl10 = nc0; cl11 = nc1;
      u32 hi0 = f2bf(nh0), lo0 = f2bf(nh0 - bf2f((u16)hi0));
      u32 hi1 = f2bf(nh1), lo1 = f2bf(nh1 - bf2f((u16)hi1));
      const int gb = sb + 8 + wv;
      size_t pidx = ((size_t)t * 32 + gb) * 64 + rp;
      astore32((u32*)hbf_h + pidx, hi0 | (hi1 << 16));
      astore32((u32*)hbf_l + pidx, lo0 | (lo1 << 16));
      astore64(cbuf + pidx, (u64)__float_as_uint(nc0) | ((u64)__float_as_uint(nc1) << 32));
      astore64((u64*)(out + (((size_t)gb * 32 + h) * 32 + w) * 128 + rp * 2),
               (u64)__float_as_uint(nh0) | ((u64)__float_as_uint(nh1) << 32));
      *(u32*)&h2h[(8 + wv) * 136 + rp * 2] = hi0 | (hi1 << 16);
      *(u32*)&h2l[(8 + wv) * 136 + rp * 2] = lo0 | (lo1 << 16);
    }

    __syncthreads();   // compiler drains vmcnt per wave before s_barrier
    if (tid == 0 && h < 31)   // architected cross-XCD release: vmcnt(0)+wbl2+store
      __hip_atomic_store(&flags[fid], w + 1, __ATOMIC_RELEASE, __HIP_MEMORY_SCOPE_AGENT);
  }
}

// ---------------------------------------------------------------------------
extern "C" void kernel_launch(void* const* d_in, const int* in_sizes, int n_in,
                              void* d_out, int out_size, void* d_ws, size_t ws_size,
                              hipStream_t stream) {
  const float* x    = (const float*)d_in[0];   // [32,32,128,128]
  const float* W    = (const float*)d_in[1];   // [768,640]
  const float* bias = (const float*)d_in[2];   // [640]
  float* out = (float*)d_out;                  // [32,32,32,128]
  char* ws = (char*)d_ws;

  size_t off = 0;
  u16*   xs_h  = (u16*)(ws + off);  off += (size_t)32768 * 512 * 2;  // 33.6 MB
  u16*   xs_l  = (u16*)(ws + off);  off += (size_t)32768 * 512 * 2;  // 33.6 MB
  u16*   WxT_h = (u16*)(ws + off);  off += (size_t)640 * 512 * 2;
  u16*   WxT_l = (u16*)(ws + off);  off += (size_t)640 * 512 * 2;
  u16*   WhT_h = (u16*)(ws + off);  off += (size_t)640 * 256 * 2;
  u16*   WhT_l = (u16*)(ws + off);  off += (size_t)640 * 256 * 2;
  float* biasp = (float*)(ws + off); off += (size_t)640 * 4;
  float* Gp    = (float*)(ws + off); off += (size_t)32768 * 640 * 4; // 83.9 MB
  u64*   cbuf  = (u64*)(ws + off);  off += (size_t)32768 * 64 * 8;   // 16.8 MB
  u16*   hbf_h = (u16*)(ws + off);  off += (size_t)32768 * 128 * 2;  // 8.4 MB
  u16*   hbf_l = (u16*)(ws + off);  off += (size_t)32768 * 128 * 2;  // 8.4 MB
  int*   flags = (int*)(ws + off);  off += 1024 * 4;
  (void)ws_size;

  hipMemsetAsync(flags, 0, 1024 * sizeof(int), stream);
  k_wprep<<<dim3(640), dim3(256), 0, stream>>>(W, bias, WxT_h, WxT_l, WhT_h, WhT_l, biasp);
  k_xgather<<<dim3(8192), dim3(256), 0, stream>>>(x, xs_h, xs_l);
  k_gemm_in<<<dim3(256, 5), dim3(256), 0, stream>>>(xs_h, xs_l, WxT_h, WxT_l, biasp, Gp);
  k_rec<<<dim3(64), dim3(512), 0, stream>>>(WhT_h, WhT_l, Gp, cbuf, hbf_h, hbf_l, out, flags);
}

// Round 2
// 591.012 us; speedup vs baseline: 2.2473x; 2.2473x over previous
//
#include <hip/hip_runtime.h>

// ---------------------------------------------------------------------------
// MultiDimensionalLSTM on MI355X.
// B=32, C=32, Y=X=128, win 4x4 -> grid 32x32 cells, F=512, R=128, gates 5R=640.
// Input projection hoisted to one split-bf16 MFMA GEMM (unchanged).
//
// R7: R6 post-mortem showed VGPR_Count=128 -> the 320 weight regs/lane spilled
// to scratch (8-wave block = 2 waves/SIMD = 256-reg cap). Fixes:
//  (a) 4-wave blocks (256 thr) = 1 wave/SIMD = 512 unified VGPR/AGPR budget.
//      N split across a sibling pair: grid 128 = (h, s batch-half, hf n-half).
//      Per block 16 batches x 320 pcols; per wave 5 n-tiles -> 320 weight regs
//      + ~110 working ~= 430 < 512. Weights genuinely register-resident
//      (VERIFY: VGPR_Count >= 384 next profile).
//  (b) DATA-AS-FLAG transport: every h/c word is written exactly once, so
//      sentinel-init (0xFF: bf16 0xFFFF / f32 0xFFFFFFFF = NaN, unreachable
//      for tanh/sig outputs and finite cells) + relaxed sc1 stores + consumers
//      polling the data words themselves. NO flags, NO release, NO wbl2 in
//      k_rec at all. Immune to R4's producer-reorder failure (no separate
//      flag to outrun the data; each 4B/8B atomic word self-announces).
//      Left dep: sibling block (same h, other n-half) + own half, both via
//      MALL. Up dep: row h-1 pair. Poll sweeps load all 16 u64 frags in
//      parallel -> one MALL RT per retry.
// ---------------------------------------------------------------------------

typedef unsigned short u16;
typedef unsigned int u32;
typedef unsigned long long u64;
typedef __attribute__((ext_vector_type(8))) short short8;     // 8 bf16 (4 VGPRs)
typedef __attribute__((ext_vector_type(8))) unsigned short us8;
typedef __attribute__((ext_vector_type(4))) float floatx4;

union Frag { u64 q[2]; short8 s; };

__device__ inline u16 f2bf(float f) {               // RNE fp32 -> bf16
  unsigned u = __float_as_uint(f);
  u += 0x7fffu + ((u >> 16) & 1u);
  return (u16)(u >> 16);
}
__device__ inline float bf2f(u16 v) { return __uint_as_float(((unsigned)v) << 16); }

__device__ inline void async16(u16* lds, const u16* g) {
  __builtin_amdgcn_global_load_lds((const __attribute__((address_space(1))) void*)g,
                                   (__attribute__((address_space(3))) void*)lds, 16, 0, 0);
}

__device__ inline float sigf(float x) { return 1.f / (1.f + __expf(-x)); }
__device__ inline float tanh_fast(float x) { return 1.f - 2.f / (__expf(2.f * x) + 1.f); }

// Relaxed agent-scope primitives: sc1 loads/stores, straight to the agent
// coherence point (MALL). No ordering semantics needed: value-as-presence.
__device__ inline u64 aload64(const u64* p) {
  return __hip_atomic_load(p, __ATOMIC_RELAXED, __HIP_MEMORY_SCOPE_AGENT);
}
__device__ inline void astore32(u32* p, u32 v) {
  __hip_atomic_store(p, v, __ATOMIC_RELAXED, __HIP_MEMORY_SCOPE_AGENT);
}
__device__ inline void astore64(u64* p, u64 v) {
  __hip_atomic_store(p, v, __ATOMIC_RELAXED, __HIP_MEMORY_SCOPE_AGENT);
}
__device__ inline u32 isbad(u64 v) {      // either 4B half still sentinel?
  return ((u32)v == 0xFFFFFFFFu) | ((u32)(v >> 32) == 0xFFFFFFFFu);
}

// Poll all 16 u64 fragment words (4 ks x 2 q x 2 planes) until every 4B unit
// is non-sentinel. Loads issue back-to-back -> one MALL RT per sweep.
#define POLLFRAGS(bh, bl, fh, fl)                                           \
  for (;;) {                                                                \
    _Pragma("unroll")                                                       \
    for (int ks = 0; ks < 4; ++ks) {                                        \
      fh[ks].q[0] = aload64((bh) + ks * 8);                                 \
      fh[ks].q[1] = aload64((bh) + ks * 8 + 1);                             \
      fl[ks].q[0] = aload64((bl) + ks * 8);                                 \
      fl[ks].q[1] = aload64((bl) + ks * 8 + 1);                             \
    }                                                                       \
    u32 badv = 0;                                                           \
    _Pragma("unroll")                                                       \
    for (int ks = 0; ks < 4; ++ks)                                          \
      badv |= isbad(fh[ks].q[0]) | isbad(fh[ks].q[1]) |                     \
              isbad(fl[ks].q[0]) | isbad(fl[ks].q[1]);                      \
    if (!badv) break;                                                       \
    __builtin_amdgcn_s_sleep(1);                                            \
    __asm__ __volatile__("" ::: "memory");                                  \
  }

// ---------------------------------------------------------------------------
// Prep 1: W [768][640] fp32 -> WxT_{h,l} [640 pcol][512 k], WhT_{h,l} [640][256],
// biasp [640]. pcol = r*5+g  <->  orig col g*128+r (gate-interleaved).
// ---------------------------------------------------------------------------
__global__ __launch_bounds__(256) void k_wprep(const float* __restrict__ W,
                                               const float* __restrict__ bias,
                                               u16* __restrict__ WxT_h, u16* __restrict__ WxT_l,
                                               u16* __restrict__ WhT_h, u16* __restrict__ WhT_l,
                                               float* __restrict__ biasp) {
  int pcol = blockIdx.x;                       // 0..639
  int col  = (pcol % 5) * 128 + pcol / 5;      // original gate column
  for (int k = threadIdx.x; k < 768; k += 256) {
    float v = W[(size_t)k * 640 + col];
    u16 hi = f2bf(v);
    u16 lo = f2bf(v - bf2f(hi));
    if (k < 512) { WxT_h[(size_t)pcol * 512 + k] = hi; WxT_l[(size_t)pcol * 512 + k] = lo; }
    else { WhT_h[(size_t)pcol * 256 + (k - 512)] = hi; WhT_l[(size_t)pcol * 256 + (k - 512)] = lo; }
  }
  if (threadIdx.x == 0) biasp[pcol] = bias[col];
}

// ---------------------------------------------------------------------------
// Prep 2: gather x [B,C,Y,X] -> xs hi/lo [t][b][f].
// xs[t][b][f] = x[b][f&31][t>>3][(t&7)*16 + (f>>5)]
// ---------------------------------------------------------------------------
__global__ __launch_bounds__(256) void k_xgather(const float* __restrict__ x,
                                                 u16* __restrict__ xs_h,
                                                 u16* __restrict__ xs_l) {
  int lane = threadIdx.x & 63;
  int pair = blockIdx.x * 4 + (threadIdx.x >> 6);  // t*32+b
  int t = pair >> 5, b = pair & 31;
  int y = t >> 3, x0 = (t & 7) * 16;
  int j = lane >> 2;
  int cbase = (lane & 3) * 8;
  const float* src = x + ((size_t)b * 32 * 128 + y) * 128 + x0 + j;
  us8 vh, vl;
#pragma unroll
  for (int u = 0; u < 8; ++u) {
    float f = src[(size_t)(cbase + u) * 16384];
    u16 hi = f2bf(f);
    vh[u] = hi;
    vl[u] = f2bf(f - bf2f(hi));
  }
  *(us8*)(xs_h + (size_t)pair * 512 + lane * 8) = vh;
  *(us8*)(xs_l + (size_t)pair * 512 + lane * 8) = vl;
}

// ---------------------------------------------------------------------------
// Input GEMM (split-bf16): M=32768, N=640, K=512. 128x128 tile, BK=32.
// ---------------------------------------------------------------------------
__global__ __launch_bounds__(256) void k_gemm_in(const u16* __restrict__ xs_h,
                                                 const u16* __restrict__ xs_l,
                                                 const u16* __restrict__ WxT_h,
                                                 const u16* __restrict__ WxT_l,
                                                 const float* __restrict__ biasp,
                                                 float* __restrict__ Gp) {
  __shared__ u16 Ah[128 * 32], Al[128 * 32];
  __shared__ u16 Bh[128 * 32], Bl[128 * 32];
  const int tid = threadIdx.x;
  const int wv = tid >> 6, lane = tid & 63;
  const int quad = lane >> 4, l16 = lane & 15;
  const int m0 = blockIdx.x * 128;
  const int n0 = blockIdx.y * 128;
  const int arow = lane >> 2;
  const int acol = (lane & 3) * 8;

  floatx4 acc[4][4] = {};

  for (int kt = 0; kt < 512; kt += 32) {
#pragma unroll
    for (int i = 0; i < 2; ++i) {
      int chunk = wv * 2 + i;
      int row = chunk * 16 + arow;
      size_t aoff = (size_t)(m0 + row) * 512 + kt + acol;
      size_t boff = (size_t)(n0 + row) * 512 + kt + acol;
      async16(&Ah[chunk * 512 + lane * 8], xs_h + aoff);
      async16(&Al[chunk * 512 + lane * 8], xs_l + aoff);
      async16(&Bh[chunk * 512 + lane * 8], WxT_h + boff);
      async16(&Bl[chunk * 512 + lane * 8], WxT_l + boff);
    }
    __syncthreads();
    short8 afh[4], afl[4], bfh[4], bfl[4];
#pragma unroll
    for (int mt = 0; mt < 4; ++mt) {
      int ro = ((wv & 1) * 64 + mt * 16 + l16) * 32 + quad * 8;
      afh[mt] = *(const short8*)&Ah[ro];
      afl[mt] = *(const short8*)&Al[ro];
    }
#pragma unroll
    for (int nt = 0; nt < 4; ++nt) {
      int ro = ((wv >> 1) * 64 + nt * 16 + l16) * 32 + quad * 8;
      bfh[nt] = *(const short8*)&Bh[ro];
      bfl[nt] = *(const short8*)&Bl[ro];
    }
#pragma unroll
    for (int mt = 0; mt < 4; ++mt)
#pragma unroll
      for (int nt = 0; nt < 4; ++nt) {
        floatx4 a = acc[mt][nt];
        a = __builtin_amdgcn_mfma_f32_16x16x32_bf16(afl[mt], bfh[nt], a, 0, 0, 0);
        a = __builtin_amdgcn_mfma_f32_16x16x32_bf16(afh[mt], bfl[nt], a, 0, 0, 0);
        a = __builtin_amdgcn_mfma_f32_16x16x32_bf16(afh[mt], bfh[nt], a, 0, 0, 0);
        acc[mt][nt] = a;
      }
    __syncthreads();
  }
#pragma unroll
  for (int nt = 0; nt < 4; ++nt) {
    int n = n0 + (wv >> 1) * 64 + nt * 16 + l16;
    float bv = biasp[n];
#pragma unroll
    for (int mt = 0; mt < 4; ++mt) {
      int m = m0 + (wv & 1) * 64 + mt * 16 + quad * 4;
#pragma unroll
      for (int r = 0; r < 4; ++r)
        Gp[(size_t)(m + r) * 640 + n] = acc[mt][nt][r] + bv;
    }
  }
}

// ---------------------------------------------------------------------------
// Persistent recurrence, batch+n sliced. Grid 128: bid = h*4 + s*2 + hf
// (lower h first). Block 256 threads = 4 waves = 1 wave/SIMD -> 512-reg
// budget; weights (5nt x 8ks x hi/lo = 320 regs/lane) register-resident.
// Block (s,hf,h): batches sb=s*16..+16, pcols hf*320..+320 (r in [hf*64,+64)).
// Transport: data-as-flag (sentinel 0xFF..), relaxed sc1 everywhere, no fences.
// ---------------------------------------------------------------------------
__global__ __launch_bounds__(256, 1) void k_rec(const u16* __restrict__ WhT_h,
                                                const u16* __restrict__ WhT_l,
                                                const float* __restrict__ Gp,
                                                u64* __restrict__ cbuf,       // [t*32+b][64] fp32 pairs
                                                u16* __restrict__ hbf_h,      // [t*32+b][128]
                                                u16* __restrict__ hbf_l,
                                                float* __restrict__ out) {
  __shared__ float Gs[16 * 324];        // 20.7 KB; stride 324 (16B-aligned rows)

  const int hf = blockIdx.x & 1;        // n-half
  const int s  = (blockIdx.x >> 1) & 1; // batch-half
  const int h  = blockIdx.x >> 2;       // row
  const int sb = s * 16;
  const int tid = threadIdx.x;
  const int wv = tid >> 6, lane = tid & 63;
  const int quad = lane >> 4, l16 = lane & 15;
  const int n0 = hf * 320 + wv * 80;    // this wave's global pcol base
  const int eb = tid >> 4;              // epilogue batch 0..15
  const int erq = tid & 15;             // epilogue r-quad (4 r's: hf*64+erq*4+u)

  // ---- Wh fragments -> registers, once. Fully static indexing. ----
  short8 Bh[5][8], Bl[5][8];
#pragma unroll
  for (int nt = 0; nt < 5; ++nt) {
    const u16* ph = WhT_h + (size_t)(n0 + nt * 16 + l16) * 256 + quad * 8;
    const u16* pl = WhT_l + (size_t)(n0 + nt * 16 + l16) * 256 + quad * 8;
#pragma unroll
    for (int ks = 0; ks < 8; ++ks) {
      Bh[nt][ks] = *(const short8*)(ph + ks * 32);
      Bl[nt][ks] = *(const short8*)(pl + ks * 32);
    }
  }

  float cl[4] = {0.f, 0.f, 0.f, 0.f};   // c_left for this thread's 4 r's

  for (int w = 0; w < 32; ++w) {
    const int t = h * 32 + w;
    const bool upok = t > 32;           // faithful off-by-one: (1,0) gets no up

    // gate-bias prefetch from Gp (plain cached loads, in flight during polls)
    float g[20];
    {
      const float* p = Gp + ((size_t)t * 32 + sb + eb) * 640 + hf * 320 + erq * 20;
#pragma unroll
      for (int i = 0; i < 5; ++i)
        *(floatx4*)&g[i * 4] = *(const floatx4*)(p + i * 4);
    }

    floatx4 acc[5] = {};
    u64 cp0 = 0, cp1 = 0;

    if (upok) {                          // up half: poll row h-1 step w
      const size_t rowb = (((size_t)(t - 32) * 32 + sb + l16) * 128 + quad * 8) >> 2;
      const u64* bh = (const u64*)hbf_h + rowb;
      const u64* bl = (const u64*)hbf_l + rowb;
      Frag fh[4], fl[4];
      POLLFRAGS(bh, bl, fh, fl);
#pragma unroll
      for (int ks = 0; ks < 4; ++ks)
#pragma unroll
        for (int nt = 0; nt < 5; ++nt) {
          floatx4 a = acc[nt];
          a = __builtin_amdgcn_mfma_f32_16x16x32_bf16(fl[ks].s, Bh[nt][ks], a, 0, 0, 0);
          a = __builtin_amdgcn_mfma_f32_16x16x32_bf16(fh[ks].s, Bl[nt][ks], a, 0, 0, 0);
          a = __builtin_amdgcn_mfma_f32_16x16x32_bf16(fh[ks].s, Bh[nt][ks], a, 0, 0, 0);
          acc[nt] = a;
        }
    }
    if (w > 0) {                         // left half: sibling + own (just made)
      const size_t rowb = (((size_t)(t - 1) * 32 + sb + l16) * 128 + quad * 8) >> 2;
      const u64* bh = (const u64*)hbf_h + rowb;
      const u64* bl = (const u64*)hbf_l + rowb;
      Frag fh[4], fl[4];
      POLLFRAGS(bh, bl, fh, fl);
#pragma unroll
      for (int ks = 0; ks < 4; ++ks)
#pragma unroll
        for (int nt = 0; nt < 5; ++nt) {
          floatx4 a = acc[nt];
          a = __builtin_amdgcn_mfma_f32_16x16x32_bf16(fl[ks].s, Bh[nt][ks + 4], a, 0, 0, 0);
          a = __builtin_amdgcn_mfma_f32_16x16x32_bf16(fh[ks].s, Bl[nt][ks + 4], a, 0, 0, 0);
          a = __builtin_amdgcn_mfma_f32_16x16x32_bf16(fh[ks].s, Bh[nt][ks + 4], a, 0, 0, 0);
          acc[nt] = a;
        }
    }

    // acc -> Gs  (C layout: row = quad*4+r -> batch, col = l16 -> pcol-local)
#pragma unroll
    for (int nt = 0; nt < 5; ++nt)
#pragma unroll
      for (int r = 0; r < 4; ++r)
        Gs[(quad * 4 + r) * 324 + wv * 80 + nt * 16 + l16] = acc[nt][r];

    if (upok) {                          // c_up poll (arrived long before now)
      const u64* ca = cbuf + ((size_t)(t - 32) * 32 + sb + eb) * 64 + hf * 32 + erq * 2;
      for (;;) {
        cp0 = aload64(ca); cp1 = aload64(ca + 1);
        if (cp0 != 0xFFFFFFFFFFFFFFFFull && cp1 != 0xFFFFFFFFFFFFFFFFull) break;
        __builtin_amdgcn_s_sleep(1);
        __asm__ __volatile__("" ::: "memory");
      }
    }
    __syncthreads();

    // ---- epilogue: thread (eb, erq) handles r = hf*64 + erq*4 + u ----
    float c1[4];
    c1[0] = __uint_as_float((u32)cp0); c1[1] = __uint_as_float((u32)(cp0 >> 32));
    c1[2] = __uint_as_float((u32)cp1); c1[3] = __uint_as_float((u32)(cp1 >> 32));
    const float* gs = &Gs[eb * 324 + erq * 20];
    float nhv[4], ncv[4];
#pragma unroll
    for (int u = 0; u < 4; ++u) {
      float gi = gs[u * 5 + 0] + g[u * 5 + 0];
      float gj = gs[u * 5 + 1] + g[u * 5 + 1];
      float ga = gs[u * 5 + 2] + g[u * 5 + 2];
      float gb = gs[u * 5 + 3] + g[u * 5 + 3];
      float go = gs[u * 5 + 4] + g[u * 5 + 4];
      float c2 = (w > 0) ? cl[u] : 0.f;
      float nc = c1[u] * sigf(ga) + c2 * sigf(gb) + sigf(gi) * tanh_fast(gj);
      ncv[u] = nc;
      nhv[u] = tanh_fast(nc) * sigf(go);
      cl[u] = nc;
    }
    u16 hh[4], ll[4];
#pragma unroll
    for (int u = 0; u < 4; ++u) {
      hh[u] = f2bf(nhv[u]);
      ll[u] = f2bf(nhv[u] - bf2f(hh[u]));
    }
    const int gbb = sb + eb;
    const size_t pidx = ((size_t)t * 32 + gbb) * 64 + hf * 32 + erq * 2;
    astore32((u32*)hbf_h + pidx,     (u32)hh[0] | ((u32)hh[1] << 16));
    astore32((u32*)hbf_h + pidx + 1, (u32)hh[2] | ((u32)hh[3] << 16));
    astore32((u32*)hbf_l + pidx,     (u32)ll[0] | ((u32)ll[1] << 16));
    astore32((u32*)hbf_l + pidx + 1, (u32)ll[2] | ((u32)ll[3] << 16));
    astore64(cbuf + pidx,     (u64)__float_as_uint(ncv[0]) | ((u64)__float_as_uint(ncv[1]) << 32));
    astore64(cbuf + pidx + 1, (u64)__float_as_uint(ncv[2]) | ((u64)__float_as_uint(ncv[3]) << 32));
    floatx4 ov; ov[0] = nhv[0]; ov[1] = nhv[1]; ov[2] = nhv[2]; ov[3] = nhv[3];
    *(floatx4*)(out + (((size_t)gbb * 32 + h) * 32 + w) * 128 + hf * 64 + erq * 4) = ov;

    __syncthreads();                     // Gs reuse next step
  }
}

// ---------------------------------------------------------------------------
extern "C" void kernel_launch(void* const* d_in, const int* in_sizes, int n_in,
                              void* d_out, int out_size, void* d_ws, size_t ws_size,
                              hipStream_t stream) {
  const float* x    = (const float*)d_in[0];   // [32,32,128,128]
  const float* W    = (const float*)d_in[1];   // [768,640]
  const float* bias = (const float*)d_in[2];   // [640]
  float* out = (float*)d_out;                  // [32,32,32,128]
  char* ws = (char*)d_ws;

  size_t off = 0;
  u16*   xs_h  = (u16*)(ws + off);  off += (size_t)32768 * 512 * 2;  // 33.6 MB
  u16*   xs_l  = (u16*)(ws + off);  off += (size_t)32768 * 512 * 2;  // 33.6 MB
  u16*   WxT_h = (u16*)(ws + off);  off += (size_t)640 * 512 * 2;
  u16*   WxT_l = (u16*)(ws + off);  off += (size_t)640 * 512 * 2;
  u16*   WhT_h = (u16*)(ws + off);  off += (size_t)640 * 256 * 2;
  u16*   WhT_l = (u16*)(ws + off);  off += (size_t)640 * 256 * 2;
  float* biasp = (float*)(ws + off); off += (size_t)640 * 4;
  float* Gp    = (float*)(ws + off); off += (size_t)32768 * 640 * 4; // 83.9 MB
  // sentinel-initialized state region (contiguous: one 32 MB memset 0xFF)
  u64*   cbuf  = (u64*)(ws + off);  off += (size_t)32768 * 64 * 8;   // 16.8 MB
  u16*   hbf_h = (u16*)(ws + off);  off += (size_t)32768 * 128 * 2;  // 8.4 MB
  u16*   hbf_l = (u16*)(ws + off);  off += (size_t)32768 * 128 * 2;  // 8.4 MB
  (void)ws_size;

  hipMemsetAsync(cbuf, 0xFF, (size_t)32768 * 64 * 8 + (size_t)32768 * 128 * 2 * 2, stream);
  k_wprep<<<dim3(640), dim3(256), 0, stream>>>(W, bias, WxT_h, WxT_l, WhT_h, WhT_l, biasp);
  k_xgather<<<dim3(8192), dim3(256), 0, stream>>>(x, xs_h, xs_l);
  k_gemm_in<<<dim3(256, 5), dim3(256), 0, stream>>>(xs_h, xs_l, WxT_h, WxT_l, biasp, Gp);
  k_rec<<<dim3(128), dim3(256), 0, stream>>>(WhT_h, WhT_l, Gp, cbuf, hbf_h, hbf_l, out);
}

// Round 3
// 570.708 us; speedup vs baseline: 2.3272x; 1.0356x over previous
//
#include <hip/hip_runtime.h>

// ---------------------------------------------------------------------------
// MultiDimensionalLSTM on MI355X.
// B=32, C=32, Y=X=128, win 4x4 -> grid 32x32 cells, F=512, R=128, gates 5R=640.
// Input projection hoisted to one split-bf16 MFMA GEMM.
//
// R8: R7 measured 6.25us/stage = TWO sequential MALL round trips per step
// (up poll, then left-sib poll, then c poll). This round:
//  (a) ONE merged sweep per step: up-h frags + sib-h frags + up-c issued as a
//      single parallel load batch, checked together. Producers of both deps
//      finish at the same wavefront instant -> one detect latency.
//  (b) Own-left K-half via LDS (double-buffered h2, XOR-swizzled): 30 MFMAs
//      run while the sweep is in flight.
//  (c) Gate-major weight retiling: wave's 5 n-tiles are (gate g, r-block) so
//      tile g's D-column l16 = r. After 5 MFMAs a lane holds ALL 5 gates of
//      its (batch,r) cells -> fully in-register epilogue. Gs LDS deleted,
//      ONE __syncthreads per step (h2 double-buffer kills the other).
//  (d) h hi/lo packed in one u32 (hb); cbuf re-laid [t][r][b] so producer
//      16B stores == consumer 16B loads. Data-as-flag sentinel transport
//      unchanged (0xFF.. = NaN patterns unreachable; proven R7).
// Weights stay register-resident: 4 waves/block = 1 wave/SIMD = 512-reg
// unified budget; 320 weight regs/lane with static indexing (AGPR-parked).
// ---------------------------------------------------------------------------

typedef unsigned short u16;
typedef unsigned int u32;
typedef unsigned long long u64;
typedef __attribute__((ext_vector_type(8))) short short8;     // 8 bf16 (4 VGPRs)
typedef __attribute__((ext_vector_type(8))) unsigned short us8;
typedef __attribute__((ext_vector_type(4))) float floatx4;

__device__ inline u16 f2bf(float f) {               // RNE fp32 -> bf16
  unsigned u = __float_as_uint(f);
  u += 0x7fffu + ((u >> 16) & 1u);
  return (u16)(u >> 16);
}
__device__ inline float bf2f(u16 v) { return __uint_as_float(((unsigned)v) << 16); }

__device__ inline void async16(u16* lds, const u16* g) {
  __builtin_amdgcn_global_load_lds((const __attribute__((address_space(1))) void*)g,
                                   (__attribute__((address_space(3))) void*)lds, 16, 0, 0);
}

__device__ inline float sigf(float x) { return 1.f / (1.f + __expf(-x)); }
__device__ inline float tanh_fast(float x) { return 1.f - 2.f / (__expf(2.f * x) + 1.f); }

// Relaxed agent-scope primitives: sc1 loads/stores straight to the MALL.
__device__ inline u64 aload64(const u64* p) {
  return __hip_atomic_load(p, __ATOMIC_RELAXED, __HIP_MEMORY_SCOPE_AGENT);
}
__device__ inline void astore32(u32* p, u32 v) {
  __hip_atomic_store(p, v, __ATOMIC_RELAXED, __HIP_MEMORY_SCOPE_AGENT);
}
__device__ inline void astore64(u64* p, u64 v) {
  __hip_atomic_store(p, v, __ATOMIC_RELAXED, __HIP_MEMORY_SCOPE_AGENT);
}
// nonzero iff either u32 half of v is the sentinel 0xFFFFFFFF.
// SWAR haszero on ~v; borrow can only originate from an already-bad lane,
// so no harmful false positives, no false negatives.
__device__ inline u64 bad32(u64 v) {
  u64 nv = ~v;
  return (nv - 0x0000000100000001ull) & ~nv & 0x8000000080000000ull;
}
// split 4 u64 of packed (hi | lo<<16) words into hi-plane / lo-plane bf16x8
__device__ inline void unpack8(const u64 q[4], short8* H, short8* L) {
  union { u32 w[4]; short8 s; } uh, ul;
#pragma unroll
  for (int i = 0; i < 4; ++i) {
    u32 a = (u32)q[i], b = (u32)(q[i] >> 32);
    uh.w[i] = (a & 0xFFFFu) | (b << 16);
    ul.w[i] = (a >> 16) | (b & 0xFFFF0000u);
  }
  *H = uh.s; *L = ul.s;
}

// ---------------------------------------------------------------------------
// Prep 1: W [768][640] fp32 -> WxT_{h,l} [640 pcol][512 k] (pcol = r*5+g,
// gate-interleaved for the input GEMM), WhT_{h,l} [640 col][256 k] in ORIGINAL
// column order (col = g*128 + r; k_rec retiles gate-major), biasp [640 pcol].
// ---------------------------------------------------------------------------
__global__ __launch_bounds__(256) void k_wprep(const float* __restrict__ W,
                                               const float* __restrict__ bias,
                                               u16* __restrict__ WxT_h, u16* __restrict__ WxT_l,
                                               u16* __restrict__ WhT_h, u16* __restrict__ WhT_l,
                                               float* __restrict__ biasp) {
  int pcol = blockIdx.x;                       // 0..639
  int col  = (pcol % 5) * 128 + pcol / 5;      // original gate column
  for (int k = threadIdx.x; k < 768; k += 256) {
    float v = W[(size_t)k * 640 + col];
    u16 hi = f2bf(v);
    u16 lo = f2bf(v - bf2f(hi));
    if (k < 512) { WxT_h[(size_t)pcol * 512 + k] = hi; WxT_l[(size_t)pcol * 512 + k] = lo; }
    else { WhT_h[(size_t)col * 256 + (k - 512)] = hi; WhT_l[(size_t)col * 256 + (k - 512)] = lo; }
  }
  if (threadIdx.x == 0) biasp[pcol] = bias[col];
}

// ---------------------------------------------------------------------------
// Prep 2: gather x [B,C,Y,X] -> xs hi/lo [t][b][f].
// xs[t][b][f] = x[b][f&31][t>>3][(t&7)*16 + (f>>5)]
// ---------------------------------------------------------------------------
__global__ __launch_bounds__(256) void k_xgather(const float* __restrict__ x,
                                                 u16* __restrict__ xs_h,
                                                 u16* __restrict__ xs_l) {
  int lane = threadIdx.x & 63;
  int pair = blockIdx.x * 4 + (threadIdx.x >> 6);  // t*32+b
  int t = pair >> 5, b = pair & 31;
  int y = t >> 3, x0 = (t & 7) * 16;
  int j = lane >> 2;
  int cbase = (lane & 3) * 8;
  const float* src = x + ((size_t)b * 32 * 128 + y) * 128 + x0 + j;
  us8 vh, vl;
#pragma unroll
  for (int u = 0; u < 8; ++u) {
    float f = src[(size_t)(cbase + u) * 16384];
    u16 hi = f2bf(f);
    vh[u] = hi;
    vl[u] = f2bf(f - bf2f(hi));
  }
  *(us8*)(xs_h + (size_t)pair * 512 + lane * 8) = vh;
  *(us8*)(xs_l + (size_t)pair * 512 + lane * 8) = vl;
}

// ---------------------------------------------------------------------------
// Input GEMM (split-bf16): M=32768, N=640, K=512. 128x128 tile, BK=32.
// Epilogue stores Gp in [t][pcol][32 b] layout (16B aligned floatx4).
// ---------------------------------------------------------------------------
__global__ __launch_bounds__(256) void k_gemm_in(const u16* __restrict__ xs_h,
                                                 const u16* __restrict__ xs_l,
                                                 const u16* __restrict__ WxT_h,
                                                 const u16* __restrict__ WxT_l,
                                                 const float* __restrict__ biasp,
                                                 float* __restrict__ Gp) {
  __shared__ u16 Ah[128 * 32], Al[128 * 32];
  __shared__ u16 Bh[128 * 32], Bl[128 * 32];
  const int tid = threadIdx.x;
  const int wv = tid >> 6, lane = tid & 63;
  const int quad = lane >> 4, l16 = lane & 15;
  const int m0 = blockIdx.x * 128;
  const int n0 = blockIdx.y * 128;
  const int arow = lane >> 2;
  const int acol = (lane & 3) * 8;

  floatx4 acc[4][4] = {};

  for (int kt = 0; kt < 512; kt += 32) {
#pragma unroll
    for (int i = 0; i < 2; ++i) {
      int chunk = wv * 2 + i;
      int row = chunk * 16 + arow;
      size_t aoff = (size_t)(m0 + row) * 512 + kt + acol;
      size_t boff = (size_t)(n0 + row) * 512 + kt + acol;
      async16(&Ah[chunk * 512 + lane * 8], xs_h + aoff);
      async16(&Al[chunk * 512 + lane * 8], xs_l + aoff);
      async16(&Bh[chunk * 512 + lane * 8], WxT_h + boff);
      async16(&Bl[chunk * 512 + lane * 8], WxT_l + boff);
    }
    __syncthreads();
    short8 afh[4], afl[4], bfh[4], bfl[4];
#pragma unroll
    for (int mt = 0; mt < 4; ++mt) {
      int ro = ((wv & 1) * 64 + mt * 16 + l16) * 32 + quad * 8;
      afh[mt] = *(const short8*)&Ah[ro];
      afl[mt] = *(const short8*)&Al[ro];
    }
#pragma unroll
    for (int nt = 0; nt < 4; ++nt) {
      int ro = ((wv >> 1) * 64 + nt * 16 + l16) * 32 + quad * 8;
      bfh[nt] = *(const short8*)&Bh[ro];
      bfl[nt] = *(const short8*)&Bl[ro];
    }
#pragma unroll
    for (int mt = 0; mt < 4; ++mt)
#pragma unroll
      for (int nt = 0; nt < 4; ++nt) {
        floatx4 a = acc[mt][nt];
        a = __builtin_amdgcn_mfma_f32_16x16x32_bf16(afl[mt], bfh[nt], a, 0, 0, 0);
        a = __builtin_amdgcn_mfma_f32_16x16x32_bf16(afh[mt], bfl[nt], a, 0, 0, 0);
        a = __builtin_amdgcn_mfma_f32_16x16x32_bf16(afh[mt], bfh[nt], a, 0, 0, 0);
        acc[mt][nt] = a;
      }
    __syncthreads();
  }
#pragma unroll
  for (int nt = 0; nt < 4; ++nt) {
    int n = n0 + (wv >> 1) * 64 + nt * 16 + l16;
    float bv = biasp[n];
#pragma unroll
    for (int mt = 0; mt < 4; ++mt) {
      int mBase = m0 + (wv & 1) * 64 + mt * 16 + quad * 4;   // 4 consecutive m, same t
      int tt = mBase >> 5, bb = mBase & 31;
      floatx4 vv;
#pragma unroll
      for (int r = 0; r < 4; ++r) vv[r] = acc[mt][nt][r] + bv;
      *(floatx4*)&Gp[((size_t)tt * 640 + n) * 32 + bb] = vv;
    }
  }
}

// ---------------------------------------------------------------------------
// Persistent recurrence. Grid 128: bid = h*4 + s*2 + hf (lower h first).
// Block 256 thr = 4 waves = 1 wave/SIMD (512-reg unified budget).
// Block (s,hf,h): batches sb..sb+16, r in [hf*64, hf*64+64).
// Wave wv: r-block r0 = hf*64 + wv*16; lane (quad,l16): r = r0+l16,
// batches b0..b0+4 (b0 = sb+quad*4). Weight tile g covers Wh cols g*128+r.
// Per step: ONE merged remote sweep (up 16 + sib 8 + c 2 u64) overlapped
// with 30 own-left MFMAs from LDS; then 90 remote-dep MFMAs; in-register
// epilogue; 1 barrier.
// ---------------------------------------------------------------------------
__global__ __launch_bounds__(256, 1) void k_rec(const u16* __restrict__ WhT_h,
                                                const u16* __restrict__ WhT_l,
                                                const float* __restrict__ Gp,
                                                u64* __restrict__ cbuf,   // f32 [t][128 r][32 b]
                                                u32* __restrict__ hb,     // [t*32+b][128 r] hi|lo<<16
                                                float* __restrict__ out) {
  __shared__ u16 h2h[2][1024], h2l[2][1024];   // [buf][16 b][64 r], XOR-swizzled

  const int hf = blockIdx.x & 1;
  const int s  = (blockIdx.x >> 1) & 1;
  const int h  = blockIdx.x >> 2;
  const int sb = s * 16;
  const int tid = threadIdx.x;
  const int wv = tid >> 6, lane = tid & 63;
  const int quad = lane >> 4, l16 = lane & 15;
  const int r0 = hf * 64 + wv * 16;
  const int rg = r0 + l16;                     // this lane's r
  const int b0 = sb + quad * 4;                // this lane's batch base

  // ---- Wh fragments -> registers, once. Static reg indexing; ks slots:
  // 0..3 = up (k 0..127); 4..5 = OWN left half (k 128+hf*64+..); 6..7 = SIB.
  short8 Bw_h[5][8], Bw_l[5][8];
#pragma unroll
  for (int g = 0; g < 5; ++g) {
    const u16* ph = WhT_h + (size_t)(g * 128 + rg) * 256 + quad * 8;
    const u16* pl = WhT_l + (size_t)(g * 128 + rg) * 256 + quad * 8;
#pragma unroll
    for (int ks = 0; ks < 8; ++ks) {
      int kk;
      if (ks < 4)      kk = ks * 32;
      else if (ks < 6) kk = 128 + hf * 64 + (ks - 4) * 32;
      else             kk = 128 + (1 - hf) * 64 + (ks - 6) * 32;
      Bw_h[g][ks] = *(const short8*)(ph + kk);
      Bw_l[g][ks] = *(const short8*)(pl + kk);
    }
  }

  float cl[4] = {0.f, 0.f, 0.f, 0.f};          // c_left, this lane's 4 cells

  for (int w = 0; w < 32; ++w) {
    const int t = h * 32 + w;
    const bool upok = t > 32;                  // faithful off-by-one
    const bool leftok = w > 0;

    // gate biases from Gp (plain cached loads; in flight during the sweep)
    floatx4 gg[5];
    {
      const float* gpb = Gp + ((size_t)t * 640 + rg * 5) * 32 + b0;
#pragma unroll
      for (int g = 0; g < 5; ++g) gg[g] = *(const floatx4*)(gpb + g * 32);
    }

    // ---- issue merged remote sweep ----
    u64 uq[4][4]; u64 sq[2][4]; u64 cq0 = 0, cq1 = 0;
    const u64* hb64 = (const u64*)hb;
    size_t ub = 0, sbase = 0, cb = 0;
    const int sk0 = (1 - hf) * 2;
    if (upok) {
      ub = (((size_t)(t - 32) * 32 + sb + l16) * 128 + quad * 8) >> 1;
      cb = (((size_t)(t - 32) * 128 + rg) * 32 + b0) >> 1;
#pragma unroll
      for (int ks = 0; ks < 4; ++ks)
#pragma unroll
        for (int i = 0; i < 4; ++i) uq[ks][i] = aload64(hb64 + ub + ks * 16 + i);
      cq0 = aload64(cbuf + cb); cq1 = aload64(cbuf + cb + 1);
    }
    if (leftok) {
      sbase = (((size_t)(t - 1) * 32 + sb + l16) * 128 + quad * 8) >> 1;
#pragma unroll
      for (int j = 0; j < 2; ++j)
#pragma unroll
        for (int i = 0; i < 4; ++i) sq[j][i] = aload64(hb64 + sbase + (sk0 + j) * 16 + i);
    }

    floatx4 acc[5] = {};

    // ---- phase A: own-left MFMAs from LDS (hides sweep latency) ----
    if (leftok) {
      const int bsel = (w - 1) & 1;
#pragma unroll
      for (int j = 0; j < 2; ++j) {
        int idx = (l16 * 64 + j * 32 + quad * 8) ^ ((l16 & 7) << 3);
        short8 ah = *(const short8*)&h2h[bsel][idx];
        short8 al = *(const short8*)&h2l[bsel][idx];
#pragma unroll
        for (int g = 0; g < 5; ++g) {
          floatx4 a = acc[g];
          a = __builtin_amdgcn_mfma_f32_16x16x32_bf16(al, Bw_h[g][4 + j], a, 0, 0, 0);
          a = __builtin_amdgcn_mfma_f32_16x16x32_bf16(ah, Bw_l[g][4 + j], a, 0, 0, 0);
          a = __builtin_amdgcn_mfma_f32_16x16x32_bf16(ah, Bw_h[g][4 + j], a, 0, 0, 0);
          acc[g] = a;
        }
      }
    }

    // ---- poll: one detect for all remote deps ----
    for (;;) {
      u64 badv = 0;
      if (upok) {
#pragma unroll
        for (int ks = 0; ks < 4; ++ks)
#pragma unroll
          for (int i = 0; i < 4; ++i) badv |= bad32(uq[ks][i]);
        badv |= bad32(cq0) | bad32(cq1);
      }
      if (leftok) {
#pragma unroll
        for (int j = 0; j < 2; ++j)
#pragma unroll
          for (int i = 0; i < 4; ++i) badv |= bad32(sq[j][i]);
      }
      if (!badv) break;
      __builtin_amdgcn_s_sleep(1);
      __asm__ __volatile__("" ::: "memory");
      if (upok) {
#pragma unroll
        for (int ks = 0; ks < 4; ++ks)
#pragma unroll
          for (int i = 0; i < 4; ++i) uq[ks][i] = aload64(hb64 + ub + ks * 16 + i);
        cq0 = aload64(cbuf + cb); cq1 = aload64(cbuf + cb + 1);
      }
      if (leftok) {
#pragma unroll
        for (int j = 0; j < 2; ++j)
#pragma unroll
          for (int i = 0; i < 4; ++i) sq[j][i] = aload64(hb64 + sbase + (sk0 + j) * 16 + i);
      }
    }

    // ---- phase B: remote-dep MFMAs ----
    if (upok) {
#pragma unroll
      for (int ks = 0; ks < 4; ++ks) {
        short8 ah, al;
        unpack8(uq[ks], &ah, &al);
#pragma unroll
        for (int g = 0; g < 5; ++g) {
          floatx4 a = acc[g];
          a = __builtin_amdgcn_mfma_f32_16x16x32_bf16(al, Bw_h[g][ks], a, 0, 0, 0);
          a = __builtin_amdgcn_mfma_f32_16x16x32_bf16(ah, Bw_l[g][ks], a, 0, 0, 0);
          a = __builtin_amdgcn_mfma_f32_16x16x32_bf16(ah, Bw_h[g][ks], a, 0, 0, 0);
          acc[g] = a;
        }
      }
    }
    if (leftok) {
#pragma unroll
      for (int j = 0; j < 2; ++j) {
        short8 ah, al;
        unpack8(sq[j], &ah, &al);
#pragma unroll
        for (int g = 0; g < 5; ++g) {
          floatx4 a = acc[g];
          a = __builtin_amdgcn_mfma_f32_16x16x32_bf16(al, Bw_h[g][6 + j], a, 0, 0, 0);
          a = __builtin_amdgcn_mfma_f32_16x16x32_bf16(ah, Bw_l[g][6 + j], a, 0, 0, 0);
          a = __builtin_amdgcn_mfma_f32_16x16x32_bf16(ah, Bw_h[g][6 + j], a, 0, 0, 0);
          acc[g] = a;
        }
      }
    }

    // ---- in-register epilogue: lane's 4 cells (b0+u, rg) ----
    float c1v[4];
    c1v[0] = __uint_as_float((u32)cq0); c1v[1] = __uint_as_float((u32)(cq0 >> 32));
    c1v[2] = __uint_as_float((u32)cq1); c1v[3] = __uint_as_float((u32)(cq1 >> 32));
    float nh[4]; u32 hpack[4];
#pragma unroll
    for (int u = 0; u < 4; ++u) {
      float gi = acc[0][u] + gg[0][u];
      float gj = acc[1][u] + gg[1][u];
      float ga = acc[2][u] + gg[2][u];
      float gb = acc[3][u] + gg[3][u];
      float go = acc[4][u] + gg[4][u];
      float c1 = upok ? c1v[u] : 0.f;
      float c2 = leftok ? cl[u] : 0.f;
      float nc = c1 * sigf(ga) + c2 * sigf(gb) + sigf(gi) * tanh_fast(gj);
      float nhv = tanh_fast(nc) * sigf(go);
      cl[u] = nc;
      nh[u] = nhv;
      u16 hi = f2bf(nhv);
      u16 lo = f2bf(nhv - bf2f(hi));
      hpack[u] = (u32)hi | ((u32)lo << 16);
    }
    // global publication (relaxed sc1; words self-announce vs sentinel)
    const size_t hbase = ((size_t)t * 32 + b0) * 128 + rg;
#pragma unroll
    for (int u = 0; u < 4; ++u) astore32(hb + hbase + (size_t)u * 128, hpack[u]);
    const size_t cw = (((size_t)t * 128 + rg) * 32 + b0) >> 1;
    astore64(cbuf + cw,     (u64)__float_as_uint(cl[0]) | ((u64)__float_as_uint(cl[1]) << 32));
    astore64(cbuf + cw + 1, (u64)__float_as_uint(cl[2]) | ((u64)__float_as_uint(cl[3]) << 32));
#pragma unroll
    for (int u = 0; u < 4; ++u)
      out[(((size_t)(b0 + u) * 32 + h) * 32 + w) * 128 + rg] = nh[u];
    // own-half h -> LDS for next step's phase A
    {
      const int bsel = w & 1;
#pragma unroll
      for (int u = 0; u < 4; ++u) {
        int bl = quad * 4 + u;
        int idx = (bl * 64 + wv * 16 + l16) ^ ((bl & 7) << 3);
        h2h[bsel][idx] = (u16)(hpack[u] & 0xFFFFu);
        h2l[bsel][idx] = (u16)(hpack[u] >> 16);
      }
    }
    __syncthreads();
  }
}

// ---------------------------------------------------------------------------
extern "C" void kernel_launch(void* const* d_in, const int* in_sizes, int n_in,
                              void* d_out, int out_size, void* d_ws, size_t ws_size,
                              hipStream_t stream) {
  const float* x    = (const float*)d_in[0];   // [32,32,128,128]
  const float* W    = (const float*)d_in[1];   // [768,640]
  const float* bias = (const float*)d_in[2];   // [640]
  float* out = (float*)d_out;                  // [32,32,32,128]
  char* ws = (char*)d_ws;

  size_t off = 0;
  u16*   xs_h  = (u16*)(ws + off);  off += (size_t)32768 * 512 * 2;  // 33.6 MB
  u16*   xs_l  = (u16*)(ws + off);  off += (size_t)32768 * 512 * 2;  // 33.6 MB
  u16*   WxT_h = (u16*)(ws + off);  off += (size_t)640 * 512 * 2;
  u16*   WxT_l = (u16*)(ws + off);  off += (size_t)640 * 512 * 2;
  u16*   WhT_h = (u16*)(ws + off);  off += (size_t)640 * 256 * 2;
  u16*   WhT_l = (u16*)(ws + off);  off += (size_t)640 * 256 * 2;
  float* biasp = (float*)(ws + off); off += (size_t)640 * 4;
  float* Gp    = (float*)(ws + off); off += (size_t)1024 * 640 * 32 * 4; // 83.9 MB
  // sentinel-initialized state region (contiguous: one 33.6 MB memset 0xFF)
  u64*   cbuf  = (u64*)(ws + off);  off += (size_t)1024 * 128 * 32 * 4;  // 16.8 MB
  u32*   hb    = (u32*)(ws + off);  off += (size_t)32768 * 128 * 4;      // 16.8 MB
  (void)ws_size;

  hipMemsetAsync(cbuf, 0xFF, (size_t)1024 * 128 * 32 * 4 + (size_t)32768 * 128 * 4, stream);
  k_wprep<<<dim3(640), dim3(256), 0, stream>>>(W, bias, WxT_h, WxT_l, WhT_h, WhT_l, biasp);
  k_xgather<<<dim3(8192), dim3(256), 0, stream>>>(x, xs_h, xs_l);
  k_gemm_in<<<dim3(256, 5), dim3(256), 0, stream>>>(xs_h, xs_l, WxT_h, WxT_l, biasp, Gp);
  k_rec<<<dim3(128), dim3(256), 0, stream>>>(WhT_h, WhT_l, Gp, cbuf, hb, out);
}